// Round 7
// baseline (619.636 us; speedup 1.0000x reference)
//
#include <hip/hip_runtime.h>
#include <hip/hip_cooperative_groups.h>
#include <math.h>

namespace cg = cooperative_groups;

#define N_NODES 100000

// counter slots
#define C_NS   0
#define C_NT   1
#define C_NE0  2
#define C_NE1  3
#define C_NE2  4

#define E0_CAP 4096
#define E1_CAP 16384
#define E2_CAP 65536
#define T_CAP  16384
#define S_CAP  4096

__device__ inline void set_insert(int v, int* map, int* list, int* ctr, int cidx, int cap) {
    int old = atomicCAS(&map[v], 0, -1);
    if (old == 0) {
        int k = atomicAdd(&ctr[cidx], 1);
        if (k < cap) list[k] = v;
        map[v] = k + 1;
    }
}

// 64-row-tile GEMM: Y[rr] = X[node(rr)] @ W for rr < R.
// node(rr) = rr<nA ? (listA?listA[rr]:rr) : listB[rr-nA]
__device__ inline void gemm_tiles(const float* __restrict__ X, const float* __restrict__ W,
                                  float* __restrict__ Y, int R, int nA,
                                  const int* __restrict__ listA, const int* __restrict__ listB,
                                  float* sWc, float* sX, int tid, int bid) {
    int rg = tid >> 4, cgc = tid & 15;
    int rowb = rg * 4;
    int c0 = cgc * 4, c1 = 64 + cgc * 4;
    for (int t = bid; t * 64 < R; t += 256) {
        int row0 = t * 64;
        float acc[4][8];
#pragma unroll
        for (int i = 0; i < 4; ++i)
#pragma unroll
            for (int j = 0; j < 8; ++j) acc[i][j] = 0.f;
        for (int k0 = 0; k0 < 128; k0 += 32) {
#pragma unroll
            for (int i = 0; i < 4; ++i) {
                int idx = i * 256 + tid;
                ((float4*)sWc)[idx] = ((const float4*)(W + (long)k0 * 128))[idx];
            }
#pragma unroll
            for (int i = 0; i < 2; ++i) {
                int idx = i * 256 + tid;   // 0..511
                int r = idx >> 3, q = idx & 7;
                int rr = row0 + r;
                float4 v = make_float4(0.f, 0.f, 0.f, 0.f);
                if (rr < R) {
                    int node = (rr < nA) ? (listA ? listA[rr] : rr) : listB[rr - nA];
                    v = *(const float4*)&X[(long)node * 128 + k0 + q * 4];
                }
                sX[r * 33 + q * 4 + 0] = v.x;
                sX[r * 33 + q * 4 + 1] = v.y;
                sX[r * 33 + q * 4 + 2] = v.z;
                sX[r * 33 + q * 4 + 3] = v.w;
            }
            __syncthreads();
#pragma unroll 4
            for (int kk = 0; kk < 32; ++kk) {
                float4 w0 = *(const float4*)&sWc[kk * 128 + c0];
                float4 w1 = *(const float4*)&sWc[kk * 128 + c1];
                float xr[4];
#pragma unroll
                for (int i = 0; i < 4; ++i) xr[i] = sX[(rowb + i) * 33 + kk];
#pragma unroll
                for (int i = 0; i < 4; ++i) {
                    acc[i][0] = fmaf(xr[i], w0.x, acc[i][0]);
                    acc[i][1] = fmaf(xr[i], w0.y, acc[i][1]);
                    acc[i][2] = fmaf(xr[i], w0.z, acc[i][2]);
                    acc[i][3] = fmaf(xr[i], w0.w, acc[i][3]);
                    acc[i][4] = fmaf(xr[i], w1.x, acc[i][4]);
                    acc[i][5] = fmaf(xr[i], w1.y, acc[i][5]);
                    acc[i][6] = fmaf(xr[i], w1.z, acc[i][6]);
                    acc[i][7] = fmaf(xr[i], w1.w, acc[i][7]);
                }
            }
            __syncthreads();
        }
#pragma unroll
        for (int i = 0; i < 4; ++i) {
            int rr = row0 + rowb + i;
            if (rr < R) {
                *(float4*)&Y[(long)rr * 128 + c0] = make_float4(acc[i][0], acc[i][1], acc[i][2], acc[i][3]);
                *(float4*)&Y[(long)rr * 128 + c1] = make_float4(acc[i][4], acc[i][5], acc[i][6], acc[i][7]);
            }
        }
    }
}

__device__ inline void scatter_edges(const float* __restrict__ g,
                                     const int* __restrict__ mapSrc,
                                     const int* __restrict__ mapDst,
                                     const int* __restrict__ cnt,
                                     const int* __restrict__ Es,
                                     const int* __restrict__ Ed,
                                     int ne, float* __restrict__ acc,
                                     int srccap, int destcap, int gtid) {
    const float4* gv = (const float4*)g;
    float4* ov = (float4*)acc;
    long total = (long)ne * 32;
    for (long idx = gtid; idx < total; idx += 65536) {
        int lane = (int)(idx & 31);
        int eid = (int)(idx >> 5);
        int s = Es[eid], d = Ed[eid];
        float w = (1.0f / sqrtf((float)cnt[s] + 1.0f)) * (1.0f / sqrtf((float)cnt[d] + 1.0f));
        int ls = mapSrc ? (mapSrc[s] - 1) : eid;
        int ld = mapDst[d] - 1;
        if (ls < 0 || ls >= srccap || ld < 0 || ld >= destcap) continue;
        float4 a = gv[(long)ls * 32 + lane];
        float* op = (float*)&ov[(long)ld * 32 + lane];
        atomicAdd(op + 0, a.x * w);
        atomicAdd(op + 1, a.y * w);
        atomicAdd(op + 2, a.z * w);
        atomicAdd(op + 3, a.w * w);
    }
}

__global__ __launch_bounds__(256) void mega_kernel(
    const float* __restrict__ x, const int* __restrict__ src, const int* __restrict__ dst,
    int e, int nchunk,
    const float* __restrict__ w1, const float* __restrict__ b1,
    const float* __restrict__ w2, const float* __restrict__ b2,
    const float* __restrict__ fcw, const float* __restrict__ fcb,
    float* __restrict__ out,
    int* ctr, int* cnt, int* mapS, int* mapT,
    int* Slist, int* Tlist, int* E0src,
    int* E1s, int* E1d, int* E2s, int* E2d,
    int* bcount, int* bbase,
    float* g1, float* h1, float* h2) {
    cg::grid_group grid = cg::this_grid();
    __shared__ float sWc[32 * 128];   // 16 KB
    __shared__ float sX[64 * 33];     // 8.4 KB
    __shared__ int sint[256];
    int tid = threadIdx.x, bid = blockIdx.x;
    int gtid = bid * 256 + tid;
    const int GS = 256 * 256;
    const int n = N_NODES;

    // ---- P0: zero ctr/cnt/mapS/mapT with seeds folded in (single writer per cell) ----
    for (int i = gtid; i < 64; i += GS) ctr[i] = (i == C_NS) ? 1 : 0;
    for (int i = gtid; i < n; i += GS) cnt[i] = 0;
    for (int i = gtid; i < n; i += GS) mapS[i] = (i == 0) ? 1 : 0;
    for (int i = gtid; i < n; i += GS) mapT[i] = 0;
    if (gtid == 0) Slist[0] = 0;
    grid.sync();

    // ---- P1: full in-degree count + E0 (dst==0) + S build ----
    {
        int e4 = e >> 2;
        for (int i = gtid; i < e4; i += GS) {
            int4 d4 = ((const int4*)dst)[i];
            atomicAdd(&cnt[d4.x], 1);
            atomicAdd(&cnt[d4.y], 1);
            atomicAdd(&cnt[d4.z], 1);
            atomicAdd(&cnt[d4.w], 1);
            int dd[4] = {d4.x, d4.y, d4.z, d4.w};
#pragma unroll
            for (int j = 0; j < 4; ++j) {
                if (dd[j] == 0) {
                    int s = src[i * 4 + j];
                    int p = atomicAdd(&ctr[C_NE0], 1);
                    if (p < E0_CAP) E0src[p] = s;
                    set_insert(s, mapS, Slist, ctr, C_NS, S_CAP);
                }
            }
        }
        for (int i = e4 * 4 + gtid; i < e; i += GS) {
            int d = dst[i];
            atomicAdd(&cnt[d], 1);
            if (d == 0) {
                int s = src[i];
                int p = atomicAdd(&ctr[C_NE0], 1);
                if (p < E0_CAP) E0src[p] = s;
                set_insert(s, mapS, Slist, ctr, C_NS, S_CAP);
            }
        }
    }
    grid.sync();

    // ---- P2: seed T := S (same local indices) ----
    if (bid == 0) {
        int nS = ctr[C_NS]; if (nS > S_CAP) nS = S_CAP;
        for (int i = tid; i < nS; i += 256) {
            int v = Slist[i];
            mapT[v] = i + 1;
            Tlist[i] = v;
        }
        if (tid == 0) ctr[C_NT] = nS;
    }
    grid.sync();

    // ---- P3: E1 pass (edges into S) + T build ----
    {
        int e4 = e >> 2;
        for (int i = gtid; i < e4; i += GS) {
            int4 d4 = ((const int4*)dst)[i];
            int dd[4] = {d4.x, d4.y, d4.z, d4.w};
#pragma unroll
            for (int j = 0; j < 4; ++j) {
                if (mapS[dd[j]] != 0) {
                    int s = src[i * 4 + j];
                    int p = atomicAdd(&ctr[C_NE1], 1);
                    if (p < E1_CAP) { E1s[p] = s; E1d[p] = dd[j]; }
                    set_insert(s, mapT, Tlist, ctr, C_NT, T_CAP);
                }
            }
        }
        for (int i = e4 * 4 + gtid; i < e; i += GS) {
            int d = dst[i];
            if (mapS[d] != 0) {
                int s = src[i];
                int p = atomicAdd(&ctr[C_NE1], 1);
                if (p < E1_CAP) { E1s[p] = s; E1d[p] = d; }
                set_insert(s, mapT, Tlist, ctr, C_NT, T_CAP);
            }
        }
    }
    grid.sync();

    // ---- P4: E2 chunk counts (chunk = 1024 edges) ----
    for (int c = bid; c < nchunk; c += 256) {
        int base = c * 1024 + tid * 4;
        int pred = 0;
        if (base + 3 < e) {
            int4 d4 = *(const int4*)&dst[base];
            pred = (mapT[d4.x] != 0) + (mapT[d4.y] != 0) + (mapT[d4.z] != 0) + (mapT[d4.w] != 0);
        } else {
            for (int j = base; j < e && j < base + 4; ++j) pred += (mapT[dst[j]] != 0);
        }
        sint[tid] = pred;
        __syncthreads();
        for (int off = 128; off > 0; off >>= 1) {
            if (tid < off) sint[tid] += sint[tid + off];
            __syncthreads();
        }
        if (tid == 0) bcount[c] = sint[0];
        __syncthreads();
    }
    grid.sync();

    // ---- P5: scan chunk counts (block 0) ----
    if (bid == 0) {
        int per = (nchunk + 255) / 256;
        int b0 = tid * per; if (b0 > nchunk) b0 = nchunk;
        int b1 = b0 + per;  if (b1 > nchunk) b1 = nchunk;
        int s = 0;
        for (int i = b0; i < b1; ++i) s += bcount[i];
        sint[tid] = s;
        __syncthreads();
        for (int off = 1; off < 256; off <<= 1) {
            int v = (tid >= off) ? sint[tid - off] : 0;
            __syncthreads();
            sint[tid] += v;
            __syncthreads();
        }
        int run = sint[tid] - s;
        for (int i = b0; i < b1; ++i) { bbase[i] = run; run += bcount[i]; }
        if (tid == 255) ctr[C_NE2] = sint[255];
    }
    grid.sync();

    // ---- P6: E2 emit (deterministic compaction) ----
    for (int c = bid; c < nchunk; c += 256) {
        int base = c * 1024 + tid * 4;
        int dd[4] = {0, 0, 0, 0}, ss[4] = {0, 0, 0, 0}, p[4] = {0, 0, 0, 0};
        if (base + 3 < e) {
            int4 d4 = *(const int4*)&dst[base];
            int4 s4 = *(const int4*)&src[base];
            dd[0] = d4.x; dd[1] = d4.y; dd[2] = d4.z; dd[3] = d4.w;
            ss[0] = s4.x; ss[1] = s4.y; ss[2] = s4.z; ss[3] = s4.w;
#pragma unroll
            for (int j = 0; j < 4; ++j) p[j] = (mapT[dd[j]] != 0);
        } else {
            for (int j = 0; j < 4; ++j) {
                int idx = base + j;
                if (idx < e) { dd[j] = dst[idx]; ss[j] = src[idx]; p[j] = (mapT[dd[j]] != 0); }
            }
        }
        int tsum = p[0] + p[1] + p[2] + p[3];
        sint[tid] = tsum;
        __syncthreads();
        for (int off = 1; off < 256; off <<= 1) {
            int v = (tid >= off) ? sint[tid - off] : 0;
            __syncthreads();
            sint[tid] += v;
            __syncthreads();
        }
        int slot = bbase[c] + sint[tid] - tsum;
#pragma unroll
        for (int j = 0; j < 4; ++j) {
            if (p[j]) {
                if (slot < E2_CAP) { E2s[slot] = ss[j]; E2d[slot] = dd[j]; }
                ++slot;
            }
        }
        __syncthreads();
    }
    grid.sync();

    // ---- P7: zero h1 + gemm1 (rows: E2 edge srcs, then T self rows) ----
    {
        int nT = ctr[C_NT]; if (nT > T_CAP) nT = T_CAP;
        int ne2 = ctr[C_NE2]; if (ne2 > E2_CAP) ne2 = E2_CAP;
        long tot = (long)nT * 128;
        for (long i = gtid; i < tot; i += GS) h1[i] = 0.f;
        gemm_tiles(x, w1, g1, ne2 + nT, ne2, E2s, Tlist, sWc, sX, tid, bid);
    }
    grid.sync();

    // ---- P8: scatter1 (edge-indexed g1 rows -> h1 by mapT) ----
    {
        int ne2 = ctr[C_NE2]; if (ne2 > E2_CAP) ne2 = E2_CAP;
        scatter_edges(g1, nullptr, mapT, cnt, E2s, E2d, ne2, h1, E2_CAP, T_CAP, gtid);
    }
    grid.sync();

    // ---- P9: fin1 (relu + self + bias) ; zero h2 ----
    {
        int nT = ctr[C_NT]; if (nT > T_CAP) nT = T_CAP;
        int nS = ctr[C_NS]; if (nS > S_CAP) nS = S_CAP;
        int ne2 = ctr[C_NE2]; if (ne2 > E2_CAP) ne2 = E2_CAP;
        long tot = (long)nT * 128;
        for (long idx = gtid; idx < tot; idx += GS) {
            int c = (int)(idx & 127);
            int t = (int)(idx >> 7);
            int v = Tlist[t];
            float s2 = 1.0f / ((float)cnt[v] + 1.0f);
            float val = h1[idx] + s2 * g1[(long)(ne2 + t) * 128 + c] + b1[c];
            h1[idx] = fmaxf(val, 0.f);
        }
        long tot2 = (long)nS * 128;
        for (long i = gtid; i < tot2; i += GS) h2[i] = 0.f;
    }
    grid.sync();

    // ---- P10: gemm2 (h1 rows identity -> g1 rows [0,nT)) ----
    {
        int nT = ctr[C_NT]; if (nT > T_CAP) nT = T_CAP;
        gemm_tiles(h1, w2, g1, nT, nT, nullptr, nullptr, sWc, sX, tid, bid);
    }
    grid.sync();

    // ---- P11: scatter2 (g1 rows by mapT -> h2 by mapS) ----
    {
        int ne1 = ctr[C_NE1]; if (ne1 > E1_CAP) ne1 = E1_CAP;
        scatter_edges(g1, mapT, mapS, cnt, E1s, E1d, ne1, h2, T_CAP, S_CAP, gtid);
    }
    grid.sync();

    // ---- P12: fin2 ----
    {
        int nS = ctr[C_NS]; if (nS > S_CAP) nS = S_CAP;
        long tot = (long)nS * 128;
        for (long idx = gtid; idx < tot; idx += GS) {
            int c = (int)(idx & 127);
            int t = (int)(idx >> 7);
            int v = Slist[t];
            float s2 = 1.0f / ((float)cnt[v] + 1.0f);
            float val = h2[idx] + s2 * g1[(long)t * 128 + c] + b2[c];   // S-member mapT idx == t
            h2[idx] = fmaxf(val, 0.f);
        }
    }
    grid.sync();

    // ---- P13: readout (block 0) ----
    if (bid == 0) {
        float* sred = sX;   // reuse
        int ne0_true = ctr[C_NE0];
        int ne0 = ne0_true < E0_CAP ? ne0_true : E0_CAP;
        float val = 0.f;
        if (tid < 128) {
            val = h2[tid] * fcw[tid];               // node 0 is S-index 0
        } else {
            int c = tid - 128;
            float s = 0.f;
            for (int k = 0; k < ne0; ++k) {
                int ls = mapS[E0src[k]] - 1;
                if (ls >= 0 && ls < S_CAP) s += h2[(long)ls * 128 + c];
            }
            int m = ne0_true < 1 ? 1 : ne0_true;
            val = (s / (float)m) * fcw[tid];
        }
        sred[tid] = val;
        __syncthreads();
        for (int o = 128; o > 0; o >>= 1) {
            if (tid < o) sred[tid] += sred[tid + o];
            __syncthreads();
        }
        if (tid == 0) out[0] = sred[0] + fcb[0];
    }
}

// ---------------- launch ----------------

extern "C" void kernel_launch(void* const* d_in, const int* in_sizes, int n_in,
                              void* d_out, int out_size, void* d_ws, size_t ws_size,
                              hipStream_t stream) {
    const float* x   = (const float*)d_in[0];
    const int*   ei  = (const int*)d_in[1];
    const float* w1  = (const float*)d_in[3];
    const float* b1  = (const float*)d_in[4];
    const float* w2  = (const float*)d_in[5];
    const float* b2  = (const float*)d_in[6];
    const float* fcw = (const float*)d_in[7];
    const float* fcb = (const float*)d_in[8];

    const int n = N_NODES;
    int e = in_sizes[1] / 2;
    const int* srcp = ei;
    const int* dstp = ei + e;
    int nchunk = (e + 1023) / 1024;

    char* ws = (char*)d_ws;
    size_t off = 0;
    auto take = [&](size_t bytes) -> void* {
        void* p = ws + off;
        off += (bytes + 255) & ~(size_t)255;
        return p;
    };
    int*   ctr   = (int*)  take(64 * 4);
    int*   cnt   = (int*)  take((size_t)n * 4);
    int*   mapS  = (int*)  take((size_t)n * 4);
    int*   mapT  = (int*)  take((size_t)n * 4);
    int*   Slist = (int*)  take((size_t)S_CAP * 4);
    int*   Tlist = (int*)  take((size_t)T_CAP * 4);
    int*   E0src = (int*)  take((size_t)E0_CAP * 4);
    int*   E1s   = (int*)  take((size_t)E1_CAP * 4);
    int*   E1d   = (int*)  take((size_t)E1_CAP * 4);
    int*   E2s   = (int*)  take((size_t)E2_CAP * 4);
    int*   E2d   = (int*)  take((size_t)E2_CAP * 4);
    int*   bcount= (int*)  take((size_t)(nchunk + 2) * 4);
    int*   bbase = (int*)  take((size_t)(nchunk + 2) * 4);
    float* g1    = (float*)take((size_t)(E2_CAP + T_CAP) * 128 * 4);
    float* h1    = (float*)take((size_t)T_CAP * 128 * 4);
    float* h2    = (float*)take((size_t)S_CAP * 128 * 4);
    (void)ws_size;

    float* out = (float*)d_out;

    void* args[] = {
        (void*)&x, (void*)&srcp, (void*)&dstp, (void*)&e, (void*)&nchunk,
        (void*)&w1, (void*)&b1, (void*)&w2, (void*)&b2, (void*)&fcw, (void*)&fcb,
        (void*)&out,
        (void*)&ctr, (void*)&cnt, (void*)&mapS, (void*)&mapT,
        (void*)&Slist, (void*)&Tlist, (void*)&E0src,
        (void*)&E1s, (void*)&E1d, (void*)&E2s, (void*)&E2d,
        (void*)&bcount, (void*)&bbase,
        (void*)&g1, (void*)&h1, (void*)&h2
    };
    hipLaunchCooperativeKernel((void*)mega_kernel, dim3(256), dim3(256), args, 0, stream);
}